// Round 6
// baseline (278.946 us; speedup 1.0000x reference)
//
#include <hip/hip_runtime.h>
#include <math.h>

#define N_NODES  50000
#define N_EDGES  600000
#define NB_SCAN  ((N_NODES + 255) / 256)   // 196

typedef __attribute__((ext_vector_type(8))) short bf16x8;
typedef __attribute__((ext_vector_type(4))) float f32x4;
typedef unsigned int uint32;

__device__ __forceinline__ unsigned short f2bf(float x) {
  uint32 u = __builtin_bit_cast(uint32, x);
  u += 0x7FFFu + ((u >> 16) & 1u);   // round-to-nearest-even
  return (unsigned short)(u >> 16);
}
__device__ __forceinline__ float bf2f(uint32 lo16) {
  return __builtin_bit_cast(float, lo16 << 16);
}
__device__ __forceinline__ uint32 pack2(float a, float b) {
  return (uint32)f2bf(a) | ((uint32)f2bf(b) << 16);
}

// ---------------- fused prep: cvt feat, cvt W1, cvt W2, zero deg + col slack ----------------
#define PREP_FEAT_BLOCKS 12500   // 3.2M uint32 / 256
#define PREP_W_BLOCKS    256     // 65536 / 256
__global__ void k_prep(const float* __restrict__ feat, unsigned short* __restrict__ featb,
                       const float* __restrict__ W1l, const float* __restrict__ W1r,
                       unsigned short* __restrict__ Wc1,
                       const float* __restrict__ W2l, const float* __restrict__ W2r,
                       unsigned short* __restrict__ Wc2,
                       int* __restrict__ deg, int* __restrict__ colSlack) {
  const int bid = blockIdx.x, t = threadIdx.x;
  if (bid < PREP_FEAT_BLOCKS) {
    int i = bid * 256 + t;
    float2 v = ((const float2*)feat)[i];
    ((uint32*)featb)[i] = pack2(v.x, v.y);
  } else if (bid < PREP_FEAT_BLOCKS + PREP_W_BLOCKS) {
    int id = (bid - PREP_FEAT_BLOCKS) * 256 + t;
    int n = id >> 8, k = id & 255;
    float v = (k < 128) ? W1l[n * 128 + k] : W1r[n * 128 + (k - 128)];
    Wc1[id] = f2bf(v);
  } else if (bid < PREP_FEAT_BLOCKS + 2 * PREP_W_BLOCKS) {
    int id = (bid - PREP_FEAT_BLOCKS - PREP_W_BLOCKS) * 256 + t;
    int n = id >> 8, k = id & 255;
    float v = (n < 128) ? W2l[n * 256 + k] : W2r[(n - 128) * 256 + k];
    Wc2[id] = f2bf(v);
  } else {
    int i = (bid - PREP_FEAT_BLOCKS - 2 * PREP_W_BLOCKS) * 256 + t;
    if (i < N_NODES) deg[i] = 0;
    if (i < 64) colSlack[i] = 0;
  }
}
#define PREP_BLOCKS (PREP_FEAT_BLOCKS + 2 * PREP_W_BLOCKS + NB_SCAN)

// ---------------- CSR build ----------------
__global__ void k_count(const int* __restrict__ dst, int* __restrict__ deg) {
  int i = blockIdx.x * 256 + threadIdx.x;
  if (i < N_EDGES) atomicAdd(&deg[dst[i]], 1);
}

__global__ void k_scanA(const int* __restrict__ deg, int* __restrict__ partial,
                        int* __restrict__ blockSums) {
  __shared__ int s[256];
  int t = threadIdx.x;
  int i = blockIdx.x * 256 + t;
  int v = (i < N_NODES) ? deg[i] : 0;
  s[t] = v; __syncthreads();
  for (int off = 1; off < 256; off <<= 1) {
    int y = (t >= off) ? s[t - off] : 0;
    __syncthreads();
    s[t] += y;
    __syncthreads();
  }
  if (i < N_NODES) partial[i] = s[t] - v;
  if (t == 255) blockSums[blockIdx.x] = s[255];
}

__global__ void k_scanB(int* __restrict__ blockSums, int nb) {
  __shared__ int s[256];
  int t = threadIdx.x;
  int v = (t < nb) ? blockSums[t] : 0;
  s[t] = v; __syncthreads();
  for (int off = 1; off < 256; off <<= 1) {
    int y = (t >= off) ? s[t - off] : 0;
    __syncthreads();
    s[t] += y;
    __syncthreads();
  }
  if (t < nb) blockSums[t] = s[t] - v;
}

__global__ void k_scanC(int* __restrict__ rowStart, const int* __restrict__ blockSums,
                        int* __restrict__ cursor) {
  int i = blockIdx.x * 256 + threadIdx.x;
  if (i < N_NODES) {
    int r = rowStart[i] + blockSums[blockIdx.x];
    rowStart[i] = r;
    cursor[i] = r;
  }
}

__global__ void k_fill(const int* __restrict__ src, const int* __restrict__ dst,
                       int* __restrict__ cursor, int* __restrict__ col) {
  int i = blockIdx.x * 256 + threadIdx.x;
  if (i < N_EDGES) {
    int p = atomicAdd(&cursor[dst[i]], 1);
    col[p] = src[i];
  }
}

// ---------------- 8-deep gather-mean core ----------------
template<int STRIDE>
__device__ __forceinline__ void gather8(const uint32* __restrict__ base,
                                        const int* __restrict__ col,
                                        int rs, int dg, int lane,
                                        float& s0, float& s1) {
  int idx[8];
  #pragma unroll
  for (int q = 0; q < 8; ++q) idx[q] = col[rs + q];
  float a0[8] = {}, a1[8] = {};
  int j = 0;
  for (; j + 8 <= dg; j += 8) {
    uint32 v[8];
    #pragma unroll
    for (int q = 0; q < 8; ++q) v[q] = base[(size_t)idx[q] * STRIDE + lane];
    #pragma unroll
    for (int q = 0; q < 8; ++q) idx[q] = col[rs + j + 8 + q];
    #pragma unroll
    for (int q = 0; q < 8; ++q) {
      a0[q] += bf2f(v[q] & 0xffffu);
      a1[q] += bf2f(v[q] >> 16);
    }
  }
  #pragma unroll
  for (int q = 0; q < 7; ++q) {
    if (j + q < dg) {
      uint32 v = base[(size_t)idx[q] * STRIDE + lane];
      a0[q] += bf2f(v & 0xffffu);
      a1[q] += bf2f(v >> 16);
    }
  }
  s0 = ((a0[0] + a0[1]) + (a0[2] + a0[3])) + ((a0[4] + a0[5]) + (a0[6] + a0[7]));
  s1 = ((a1[0] + a1[1]) + (a1[2] + a1[3])) + ((a1[4] + a1[5]) + (a1[6] + a1[7]));
}

// ---------------- layer-1 aggregation: one wave per node over featb ----------------
__global__ void k_agg1(const unsigned short* __restrict__ x, const int* __restrict__ rowStart,
                       const int* __restrict__ deg, const int* __restrict__ col,
                       unsigned short* __restrict__ agg) {
  int lane = threadIdx.x & 63;
  int n = blockIdx.x * 4 + (threadIdx.x >> 6);
  int rs = rowStart[n], dg = deg[n];
  float s0, s1;
  gather8<64>((const uint32*)x, col, rs, dg, lane, s0, s1);
  float inv = 1.0f / fmaxf((float)dg, 1.0f);
  ((uint32*)agg)[(size_t)n * 64 + lane] = pack2(s0 * inv, s1 * inv);
}

// ---------------- MFMA GEMM with LDS-staged W and register-resident A ----------------
// [Yl|Yr](bf16, row-stride ldy) = [A0|A1](bf16, K=256) @ W(bf16,[256][256])^T
// block = 256 thr = 4 waves; wave = 32 rows x 256 cols.
// A fragments (full K) are loaded into registers ONCE at entry; W is staged in two
// 64KB halves via global_load_lds (LDS chunk-transposed [kchunk][n] => ds_read_b128
// bank-conflict-free). Compute loop touches only LDS + MFMA.
template<bool NORM>
__global__ __launch_bounds__(256, 2) void k_gemm(
    const unsigned short* __restrict__ A0, const unsigned short* __restrict__ A1,
    int lda, const unsigned short* __restrict__ W, const float* __restrict__ bias,
    unsigned short* __restrict__ Yl, unsigned short* __restrict__ Yr, int ldy) {
  __shared__ unsigned short Ws[128 * 256];  // 64 KB
  const int t = threadIdx.x;
  const int lane = t & 63, w = t >> 6;
  const int mi = lane & 15, quad = lane >> 4;
  const int m0 = blockIdx.x * 128 + w * 32;

  // kick off W half-0 staging first (async -> LDS, counted by vmcnt)
  {
    const unsigned short* gb = W;
    #pragma unroll
    for (int i = 0; i < 16; ++i) {
      int chunk0 = (w * 16 + i) * 64;          // wave-uniform
      int j = chunk0 >> 7;
      int n0 = chunk0 & 127;
      const unsigned short* gp = gb + (size_t)(n0 + lane) * 256 + j * 8;
      unsigned short* lp = Ws + (size_t)chunk0 * 8;
      __builtin_amdgcn_global_load_lds(
          (const __attribute__((address_space(1))) void*)gp,
          (__attribute__((address_space(3))) void*)lp, 16, 0, 0);
    }
  }
  // load ALL A fragments into registers (independent, overlap with W staging)
  bf16x8 afr[2][8];
  #pragma unroll
  for (int c = 0; c < 8; ++c) {
    const unsigned short* ap = (c < 4) ? (A0 + c * 32) : (A1 + (c - 4) * 32);
    afr[0][c] = *(const bf16x8*)(ap + (size_t)(m0 + mi) * lda + quad * 8);
    afr[1][c] = *(const bf16x8*)(ap + (size_t)(m0 + 16 + mi) * lda + quad * 8);
  }

  f32x4 acc[2][16];
  #pragma unroll
  for (int rt = 0; rt < 2; ++rt)
    #pragma unroll
    for (int a = 0; a < 16; ++a) acc[rt][a] = (f32x4){0.f, 0.f, 0.f, 0.f};

  for (int half = 0; half < 2; ++half) {
    __syncthreads();   // drains global_load_lds (and, first time, the A loads)
    #pragma unroll
    for (int c = 0; c < 8; ++c) {
      #pragma unroll
      for (int nt = 0; nt < 8; ++nt) {
        bf16x8 b = *(const bf16x8*)(Ws + ((size_t)(c * 4 + quad) * 128 + nt * 16 + mi) * 8);
        int a = half * 8 + nt;
        acc[0][a] = __builtin_amdgcn_mfma_f32_16x16x32_bf16(afr[0][c], b, acc[0][a], 0, 0, 0);
        acc[1][a] = __builtin_amdgcn_mfma_f32_16x16x32_bf16(afr[1][c], b, acc[1][a], 0, 0, 0);
      }
    }
    if (half == 0) {
      __syncthreads();   // everyone done reading Ws before restage
      const unsigned short* gb = W + (size_t)128 * 256;
      #pragma unroll
      for (int i = 0; i < 16; ++i) {
        int chunk0 = (w * 16 + i) * 64;
        int j = chunk0 >> 7;
        int n0 = chunk0 & 127;
        const unsigned short* gp = gb + (size_t)(n0 + lane) * 256 + j * 8;
        unsigned short* lp = Ws + (size_t)chunk0 * 8;
        __builtin_amdgcn_global_load_lds(
            (const __attribute__((address_space(1))) void*)gp,
            (__attribute__((address_space(3))) void*)lp, 16, 0, 0);
      }
    }
  }

  if (NORM) {
    float ss[2][4] = {};
    #pragma unroll
    for (int a = 0; a < 16; ++a) {
      float bv = bias[a * 16 + mi];
      #pragma unroll
      for (int rt = 0; rt < 2; ++rt)
        #pragma unroll
        for (int r = 0; r < 4; ++r) {
          float v = acc[rt][a][r] + bv;
          acc[rt][a][r] = v;
          ss[rt][r] += v * v;
        }
    }
    #pragma unroll
    for (int rt = 0; rt < 2; ++rt)
      #pragma unroll
      for (int r = 0; r < 4; ++r) {
        float s = ss[rt][r];
        s += __shfl_xor(s, 1, 64);
        s += __shfl_xor(s, 2, 64);
        s += __shfl_xor(s, 4, 64);
        s += __shfl_xor(s, 8, 64);
        ss[rt][r] = 1.0f / fmaxf(sqrtf(s), 1e-12f);
      }
    #pragma unroll
    for (int a = 0; a < 16; ++a)
      #pragma unroll
      for (int rt = 0; rt < 2; ++rt)
        #pragma unroll
        for (int r = 0; r < 4; ++r)
          acc[rt][a][r] = fmaxf(acc[rt][a][r] * ss[rt][r], 0.f);
  }

  #pragma unroll
  for (int rt = 0; rt < 2; ++rt)
    #pragma unroll
    for (int r = 0; r < 4; ++r) {
      int row = m0 + rt * 16 + quad * 4 + r;
      if (row < N_NODES) {
        #pragma unroll
        for (int a = 0; a < 16; ++a) {
          unsigned short* Y = (a < 8) ? Yl : Yr;
          Y[(size_t)row * ldy + (a & 7) * 16 + mi] = f2bf(acc[rt][a][r]);
        }
      }
    }
}

// ---------------- fused layer-2 tail ----------------
__global__ void k_final(const unsigned short* __restrict__ Tl, const unsigned short* __restrict__ Tr,
                        const int* __restrict__ rowStart, const int* __restrict__ deg,
                        const int* __restrict__ col,
                        const float* __restrict__ b2, const float* __restrict__ Wfc,
                        const float* __restrict__ bfc, float* __restrict__ out) {
  int lane = threadIdx.x & 63;
  int n = blockIdx.x * 4 + (threadIdx.x >> 6);
  int rs = rowStart[n], dg = deg[n];
  float s0, s1;
  gather8<64>((const uint32*)Tl, col, rs, dg, lane, s0, s1);
  float inv = 1.0f / fmaxf((float)dg, 1.0f);
  uint32 tv = ((const uint32*)Tr)[(size_t)n * 64 + lane];
  int d = lane * 2;
  float h0 = s0 * inv + bf2f(tv & 0xffffu) + b2[d];
  float h1 = s1 * inv + bf2f(tv >> 16) + b2[d + 1];
  float ss = h0 * h0 + h1 * h1;
  #pragma unroll
  for (int m = 1; m < 64; m <<= 1) ss += __shfl_xor(ss, m, 64);
  float iv = 1.0f / fmaxf(sqrtf(ss), 1e-12f);
  h0 *= iv; h1 *= iv;
  float p0 = h0 * Wfc[d] + h1 * Wfc[d + 1];
  float p1 = h0 * Wfc[128 + d] + h1 * Wfc[128 + d + 1];
  #pragma unroll
  for (int m = 1; m < 64; m <<= 1) {
    p0 += __shfl_xor(p0, m, 64);
    p1 += __shfl_xor(p1, m, 64);
  }
  if (lane == 0) {
    float l0 = p0 + bfc[0], l1 = p1 + bfc[1];
    float mx = fmaxf(l0, l1);
    float e0 = expf(l0 - mx), e1 = expf(l1 - mx);
    float s = 1.0f / (e0 + e1);
    out[(size_t)n * 2 + 0] = e0 * s;
    out[(size_t)n * 2 + 1] = e1 * s;
  }
}

extern "C" void kernel_launch(void* const* d_in, const int* in_sizes, int n_in,
                              void* d_out, int out_size, void* d_ws, size_t ws_size,
                              hipStream_t stream) {
  const float* feat = (const float*)d_in[0];
  const int* eidx = (const int*)d_in[1];
  const int* src = eidx;
  const int* dst = eidx + N_EDGES;
  const float* W1l = (const float*)d_in[2];
  const float* b1  = (const float*)d_in[3];
  const float* W1r = (const float*)d_in[4];
  const float* W2l = (const float*)d_in[5];
  const float* b2  = (const float*)d_in[6];
  const float* W2r = (const float*)d_in[7];
  const float* Wfc = (const float*)d_in[8];
  const float* bfc = (const float*)d_in[9];
  float* out = (float*)d_out;

  // workspace layout (all 16B aligned)
  int* deg       = (int*)d_ws;
  int* rowStart  = deg + 50176;
  int* cursor    = rowStart + 50176;
  int* blockSums = cursor + 50176;
  int* col       = blockSums + 256;                        // 600064 (64 slack, zeroed by k_prep)
  unsigned short* featb = (unsigned short*)(col + 600064); // 50000*128
  unsigned short* agg1b = featb + 6400000;                 // 50000*128
  unsigned short* h1b   = agg1b + 6400000;                 // 50000*256
  unsigned short* Tlb   = h1b + 12800000;                  // 50000*128
  unsigned short* Trb   = Tlb + 6400000;                   // 50000*128
  unsigned short* Wc1   = Trb + 6400000;                   // 256*256
  unsigned short* Wc2   = Wc1 + 65536;                     // 256*256

  k_prep<<<PREP_BLOCKS, 256, 0, stream>>>(feat, featb, W1l, W1r, Wc1,
                                          W2l, W2r, Wc2, deg, col + N_EDGES);
  k_count<<<(N_EDGES + 255) / 256, 256, 0, stream>>>(dst, deg);
  k_scanA<<<NB_SCAN, 256, 0, stream>>>(deg, rowStart, blockSums);
  k_scanB<<<1, 256, 0, stream>>>(blockSums, NB_SCAN);
  k_scanC<<<NB_SCAN, 256, 0, stream>>>(rowStart, blockSums, cursor);
  k_fill<<<(N_EDGES + 255) / 256, 256, 0, stream>>>(src, dst, cursor, col);

  k_agg1<<<N_NODES / 4, 256, 0, stream>>>(featb, rowStart, deg, col, agg1b);
  // layer 1: Yl/Yr are halves of the same h1 buffer (row stride 256)
  k_gemm<true><<<(N_NODES + 127) / 128, 256, 0, stream>>>(
      agg1b, featb, 128, Wc1, b1, h1b, h1b + 128, 256);
  // layer 2: split outputs into contiguous Tl / Tr (row stride 128)
  k_gemm<false><<<(N_NODES + 127) / 128, 256, 0, stream>>>(
      h1b, h1b + 128, 256, Wc2, nullptr, Tlb, Trb, 128);
  k_final<<<N_NODES / 4, 256, 0, stream>>>(Tlb, Trb, rowStart, deg, col, b2, Wfc, bfc, out);
}

// Round 7
// 277.857 us; speedup vs baseline: 1.0039x; 1.0039x over previous
//
#include <hip/hip_runtime.h>
#include <math.h>

#define N_NODES  50000
#define N_EDGES  600000
#define NB_SCAN  ((N_NODES + 255) / 256)   // 196

typedef __attribute__((ext_vector_type(8))) short bf16x8;
typedef __attribute__((ext_vector_type(4))) float f32x4;
typedef unsigned int uint32;

__device__ __forceinline__ unsigned short f2bf(float x) {
  uint32 u = __builtin_bit_cast(uint32, x);
  u += 0x7FFFu + ((u >> 16) & 1u);   // round-to-nearest-even
  return (unsigned short)(u >> 16);
}
__device__ __forceinline__ float bf2f(uint32 lo16) {
  return __builtin_bit_cast(float, lo16 << 16);
}
__device__ __forceinline__ uint32 pack2(float a, float b) {
  return (uint32)f2bf(a) | ((uint32)f2bf(b) << 16);
}

// ---------------- fused prep: cvt feat, cvt W1, cvt W2, zero deg + col slack ----------------
#define PREP_FEAT_BLOCKS 12500   // 3.2M uint32 / 256
#define PREP_W_BLOCKS    256     // 65536 / 256
__global__ void k_prep(const float* __restrict__ feat, unsigned short* __restrict__ featb,
                       const float* __restrict__ W1l, const float* __restrict__ W1r,
                       unsigned short* __restrict__ Wc1,
                       const float* __restrict__ W2l, const float* __restrict__ W2r,
                       unsigned short* __restrict__ Wc2,
                       int* __restrict__ deg, int* __restrict__ colSlack) {
  const int bid = blockIdx.x, t = threadIdx.x;
  if (bid < PREP_FEAT_BLOCKS) {
    int i = bid * 256 + t;
    float2 v = ((const float2*)feat)[i];
    ((uint32*)featb)[i] = pack2(v.x, v.y);
  } else if (bid < PREP_FEAT_BLOCKS + PREP_W_BLOCKS) {
    int id = (bid - PREP_FEAT_BLOCKS) * 256 + t;
    int n = id >> 8, k = id & 255;
    float v = (k < 128) ? W1l[n * 128 + k] : W1r[n * 128 + (k - 128)];
    Wc1[id] = f2bf(v);
  } else if (bid < PREP_FEAT_BLOCKS + 2 * PREP_W_BLOCKS) {
    int id = (bid - PREP_FEAT_BLOCKS - PREP_W_BLOCKS) * 256 + t;
    int n = id >> 8, k = id & 255;
    float v = (n < 128) ? W2l[n * 256 + k] : W2r[(n - 128) * 256 + k];
    Wc2[id] = f2bf(v);
  } else {
    int i = (bid - PREP_FEAT_BLOCKS - 2 * PREP_W_BLOCKS) * 256 + t;
    if (i < N_NODES) deg[i] = 0;
    if (i < 64) colSlack[i] = 0;
  }
}
#define PREP_BLOCKS (PREP_FEAT_BLOCKS + 2 * PREP_W_BLOCKS + NB_SCAN)

// ---------------- CSR build ----------------
__global__ void k_count(const int* __restrict__ dst, int* __restrict__ deg) {
  int i = blockIdx.x * 256 + threadIdx.x;
  if (i < N_EDGES) atomicAdd(&deg[dst[i]], 1);
}

__global__ void k_scanA(const int* __restrict__ deg, int* __restrict__ partial,
                        int* __restrict__ blockSums) {
  __shared__ int s[256];
  int t = threadIdx.x;
  int i = blockIdx.x * 256 + t;
  int v = (i < N_NODES) ? deg[i] : 0;
  s[t] = v; __syncthreads();
  for (int off = 1; off < 256; off <<= 1) {
    int y = (t >= off) ? s[t - off] : 0;
    __syncthreads();
    s[t] += y;
    __syncthreads();
  }
  if (i < N_NODES) partial[i] = s[t] - v;
  if (t == 255) blockSums[blockIdx.x] = s[255];
}

__global__ void k_scanB(int* __restrict__ blockSums, int nb) {
  __shared__ int s[256];
  int t = threadIdx.x;
  int v = (t < nb) ? blockSums[t] : 0;
  s[t] = v; __syncthreads();
  for (int off = 1; off < 256; off <<= 1) {
    int y = (t >= off) ? s[t - off] : 0;
    __syncthreads();
    s[t] += y;
    __syncthreads();
  }
  if (t < nb) blockSums[t] = s[t] - v;
}

__global__ void k_scanC(int* __restrict__ rowStart, const int* __restrict__ blockSums,
                        int* __restrict__ cursor) {
  int i = blockIdx.x * 256 + threadIdx.x;
  if (i < N_NODES) {
    int r = rowStart[i] + blockSums[blockIdx.x];
    rowStart[i] = r;
    cursor[i] = r;
  }
}

__global__ void k_fill(const int* __restrict__ src, const int* __restrict__ dst,
                       int* __restrict__ cursor, int* __restrict__ col) {
  int i = blockIdx.x * 256 + threadIdx.x;
  if (i < N_EDGES) {
    int p = atomicAdd(&cursor[dst[i]], 1);
    col[p] = src[i];
  }
}

// ---------------- 8-deep gather-mean core ----------------
template<int STRIDE>
__device__ __forceinline__ void gather8(const uint32* __restrict__ base,
                                        const int* __restrict__ col,
                                        int rs, int dg, int lane,
                                        float& s0, float& s1) {
  int idx[8];
  #pragma unroll
  for (int q = 0; q < 8; ++q) idx[q] = col[rs + q];
  float a0[8] = {}, a1[8] = {};
  int j = 0;
  for (; j + 8 <= dg; j += 8) {
    uint32 v[8];
    #pragma unroll
    for (int q = 0; q < 8; ++q) v[q] = base[(size_t)idx[q] * STRIDE + lane];
    #pragma unroll
    for (int q = 0; q < 8; ++q) idx[q] = col[rs + j + 8 + q];
    #pragma unroll
    for (int q = 0; q < 8; ++q) {
      a0[q] += bf2f(v[q] & 0xffffu);
      a1[q] += bf2f(v[q] >> 16);
    }
  }
  #pragma unroll
  for (int q = 0; q < 7; ++q) {
    if (j + q < dg) {
      uint32 v = base[(size_t)idx[q] * STRIDE + lane];
      a0[q] += bf2f(v & 0xffffu);
      a1[q] += bf2f(v >> 16);
    }
  }
  s0 = ((a0[0] + a0[1]) + (a0[2] + a0[3])) + ((a0[4] + a0[5]) + (a0[6] + a0[7]));
  s1 = ((a1[0] + a1[1]) + (a1[2] + a1[3])) + ((a1[4] + a1[5]) + (a1[6] + a1[7]));
}

// ---------------- layer-1 aggregation: one wave per node over featb ----------------
__global__ void k_agg1(const unsigned short* __restrict__ x, const int* __restrict__ rowStart,
                       const int* __restrict__ deg, const int* __restrict__ col,
                       unsigned short* __restrict__ agg) {
  int lane = threadIdx.x & 63;
  int n = blockIdx.x * 4 + (threadIdx.x >> 6);
  int rs = rowStart[n], dg = deg[n];
  float s0, s1;
  gather8<64>((const uint32*)x, col, rs, dg, lane, s0, s1);
  float inv = 1.0f / fmaxf((float)dg, 1.0f);
  ((uint32*)agg)[(size_t)n * 64 + lane] = pack2(s0 * inv, s1 * inv);
}

// ---------------- MFMA GEMM: K-split staging, register-resident A ----------------
// [Yl|Yr](bf16, row-stride ldy) = [A0|A1](bf16, K=256) @ W(bf16,[256][256])^T
// block = 256 thr = 4 waves; wave = 16 rows x 256 cols; block = 64 rows; grid 782.
// K is split in two halves of 128; half h needs only A_h (4 frags/wave, 16 VGPRs).
// W half-K (all 256 cols x 128 k = 64 KB) staged via global_load_lds, LDS layout
// [q'=8k-chunk 0..15][n 0..255] in 16B units => ds_read_b128 conflict-free
// (same bank pattern as R5's measured-zero-conflict layout).
// acc = 16 f32x4 = 64 AGPRs; VGPRs ~ 16(A cur)+16(A next)+addr << 128: no spill.
template<bool NORM>
__global__ __launch_bounds__(256, 2) void k_gemm(
    const unsigned short* __restrict__ A0, const unsigned short* __restrict__ A1,
    int lda, const unsigned short* __restrict__ W, const float* __restrict__ bias,
    unsigned short* __restrict__ Yl, unsigned short* __restrict__ Yr, int ldy) {
  __shared__ unsigned short Ws[16 * 256 * 8];  // 64 KB
  const int t = threadIdx.x;
  const int lane = t & 63, w = t >> 6;
  const int mi = lane & 15, quad = lane >> 4;
  const int m0 = blockIdx.x * 64 + w * 16;
  const int rowA = min(m0 + mi, N_NODES - 1);

  // stage W K-half 0: chunks ch = q'*256 + n  <->  W[n][q'*8 .. +8)
  #pragma unroll
  for (int i = 0; i < 16; ++i) {
    int ch0 = (w * 16 + i) * 64;             // wave-uniform
    int qp = ch0 >> 8, n0 = ch0 & 255;
    const unsigned short* gp = W + (size_t)(n0 + lane) * 256 + qp * 8;
    unsigned short* lp = Ws + (size_t)ch0 * 8;
    __builtin_amdgcn_global_load_lds(
        (const __attribute__((address_space(1))) void*)gp,
        (__attribute__((address_space(3))) void*)lp, 16, 0, 0);
  }
  // A fragments for K-half 0 (k 0..127 -> A0)
  bf16x8 af0[4];
  #pragma unroll
  for (int c = 0; c < 4; ++c)
    af0[c] = *(const bf16x8*)(A0 + (size_t)rowA * lda + c * 32 + quad * 8);

  f32x4 acc[16];
  #pragma unroll
  for (int nt = 0; nt < 16; ++nt) acc[nt] = (f32x4){0.f, 0.f, 0.f, 0.f};

  __syncthreads();   // W0 + af0 ready

  // issue A fragments for K-half 1 now (overlaps half-0 compute)
  bf16x8 af1[4];
  #pragma unroll
  for (int c = 0; c < 4; ++c)
    af1[c] = *(const bf16x8*)(A1 + (size_t)rowA * lda + c * 32 + quad * 8);

  #pragma unroll
  for (int c = 0; c < 4; ++c)
    #pragma unroll
    for (int nt = 0; nt < 16; ++nt) {
      bf16x8 b = *(const bf16x8*)(Ws + ((size_t)(c * 4 + quad) * 256 + nt * 16 + mi) * 8);
      acc[nt] = __builtin_amdgcn_mfma_f32_16x16x32_bf16(af0[c], b, acc[nt], 0, 0, 0);
    }

  __syncthreads();   // all waves done reading W0

  // stage W K-half 1
  #pragma unroll
  for (int i = 0; i < 16; ++i) {
    int ch0 = (w * 16 + i) * 64;
    int qp = ch0 >> 8, n0 = ch0 & 255;
    const unsigned short* gp = W + (size_t)(n0 + lane) * 256 + 128 + qp * 8;
    unsigned short* lp = Ws + (size_t)ch0 * 8;
    __builtin_amdgcn_global_load_lds(
        (const __attribute__((address_space(1))) void*)gp,
        (__attribute__((address_space(3))) void*)lp, 16, 0, 0);
  }
  __syncthreads();   // W1 ready (af1 long since arrived)

  #pragma unroll
  for (int c = 0; c < 4; ++c)
    #pragma unroll
    for (int nt = 0; nt < 16; ++nt) {
      bf16x8 b = *(const bf16x8*)(Ws + ((size_t)(c * 4 + quad) * 256 + nt * 16 + mi) * 8);
      acc[nt] = __builtin_amdgcn_mfma_f32_16x16x32_bf16(af1[c], b, acc[nt], 0, 0, 0);
    }

  if (NORM) {
    float ss[4] = {};
    #pragma unroll
    for (int nt = 0; nt < 16; ++nt) {
      float bv = bias[nt * 16 + mi];
      #pragma unroll
      for (int r = 0; r < 4; ++r) {
        float v = acc[nt][r] + bv;
        acc[nt][r] = v;
        ss[r] += v * v;
      }
    }
    #pragma unroll
    for (int r = 0; r < 4; ++r) {
      float s = ss[r];
      s += __shfl_xor(s, 1, 64);
      s += __shfl_xor(s, 2, 64);
      s += __shfl_xor(s, 4, 64);
      s += __shfl_xor(s, 8, 64);
      ss[r] = 1.0f / fmaxf(sqrtf(s), 1e-12f);
    }
    #pragma unroll
    for (int nt = 0; nt < 16; ++nt)
      #pragma unroll
      for (int r = 0; r < 4; ++r)
        acc[nt][r] = fmaxf(acc[nt][r] * ss[r], 0.f);
  }

  #pragma unroll
  for (int r = 0; r < 4; ++r) {
    int row = m0 + quad * 4 + r;
    if (row < N_NODES) {
      #pragma unroll
      for (int nt = 0; nt < 16; ++nt) {
        unsigned short* Y = (nt < 8) ? Yl : Yr;
        Y[(size_t)row * ldy + (nt & 7) * 16 + mi] = f2bf(acc[nt][r]);
      }
    }
  }
}

// ---------------- fused layer-2 tail ----------------
__global__ void k_final(const unsigned short* __restrict__ Tl, const unsigned short* __restrict__ Tr,
                        const int* __restrict__ rowStart, const int* __restrict__ deg,
                        const int* __restrict__ col,
                        const float* __restrict__ b2, const float* __restrict__ Wfc,
                        const float* __restrict__ bfc, float* __restrict__ out) {
  int lane = threadIdx.x & 63;
  int n = blockIdx.x * 4 + (threadIdx.x >> 6);
  int rs = rowStart[n], dg = deg[n];
  float s0, s1;
  gather8<64>((const uint32*)Tl, col, rs, dg, lane, s0, s1);
  float inv = 1.0f / fmaxf((float)dg, 1.0f);
  uint32 tv = ((const uint32*)Tr)[(size_t)n * 64 + lane];
  int d = lane * 2;
  float h0 = s0 * inv + bf2f(tv & 0xffffu) + b2[d];
  float h1 = s1 * inv + bf2f(tv >> 16) + b2[d + 1];
  float ss = h0 * h0 + h1 * h1;
  #pragma unroll
  for (int m = 1; m < 64; m <<= 1) ss += __shfl_xor(ss, m, 64);
  float iv = 1.0f / fmaxf(sqrtf(ss), 1e-12f);
  h0 *= iv; h1 *= iv;
  float p0 = h0 * Wfc[d] + h1 * Wfc[d + 1];
  float p1 = h0 * Wfc[128 + d] + h1 * Wfc[128 + d + 1];
  #pragma unroll
  for (int m = 1; m < 64; m <<= 1) {
    p0 += __shfl_xor(p0, m, 64);
    p1 += __shfl_xor(p1, m, 64);
  }
  if (lane == 0) {
    float l0 = p0 + bfc[0], l1 = p1 + bfc[1];
    float mx = fmaxf(l0, l1);
    float e0 = expf(l0 - mx), e1 = expf(l1 - mx);
    float s = 1.0f / (e0 + e1);
    out[(size_t)n * 2 + 0] = e0 * s;
    out[(size_t)n * 2 + 1] = e1 * s;
  }
}

extern "C" void kernel_launch(void* const* d_in, const int* in_sizes, int n_in,
                              void* d_out, int out_size, void* d_ws, size_t ws_size,
                              hipStream_t stream) {
  const float* feat = (const float*)d_in[0];
  const int* eidx = (const int*)d_in[1];
  const int* src = eidx;
  const int* dst = eidx + N_EDGES;
  const float* W1l = (const float*)d_in[2];
  const float* b1  = (const float*)d_in[3];
  const float* W1r = (const float*)d_in[4];
  const float* W2l = (const float*)d_in[5];
  const float* b2  = (const float*)d_in[6];
  const float* W2r = (const float*)d_in[7];
  const float* Wfc = (const float*)d_in[8];
  const float* bfc = (const float*)d_in[9];
  float* out = (float*)d_out;

  // workspace layout (all 16B aligned)
  int* deg       = (int*)d_ws;
  int* rowStart  = deg + 50176;
  int* cursor    = rowStart + 50176;
  int* blockSums = cursor + 50176;
  int* col       = blockSums + 256;                        // 600064 (64 slack, zeroed by k_prep)
  unsigned short* featb = (unsigned short*)(col + 600064); // 50000*128
  unsigned short* agg1b = featb + 6400000;                 // 50000*128
  unsigned short* h1b   = agg1b + 6400000;                 // 50000*256
  unsigned short* Tlb   = h1b + 12800000;                  // 50000*128
  unsigned short* Trb   = Tlb + 6400000;                   // 50000*128
  unsigned short* Wc1   = Trb + 6400000;                   // 256*256
  unsigned short* Wc2   = Wc1 + 65536;                     // 256*256

  k_prep<<<PREP_BLOCKS, 256, 0, stream>>>(feat, featb, W1l, W1r, Wc1,
                                          W2l, W2r, Wc2, deg, col + N_EDGES);
  k_count<<<(N_EDGES + 255) / 256, 256, 0, stream>>>(dst, deg);
  k_scanA<<<NB_SCAN, 256, 0, stream>>>(deg, rowStart, blockSums);
  k_scanB<<<1, 256, 0, stream>>>(blockSums, NB_SCAN);
  k_scanC<<<NB_SCAN, 256, 0, stream>>>(rowStart, blockSums, cursor);
  k_fill<<<(N_EDGES + 255) / 256, 256, 0, stream>>>(src, dst, cursor, col);

  k_agg1<<<N_NODES / 4, 256, 0, stream>>>(featb, rowStart, deg, col, agg1b);
  // layer 1: K-half0 A = agg1b, K-half1 A = featb (both lda=128)
  k_gemm<true><<<(N_NODES + 63) / 64, 256, 0, stream>>>(
      agg1b, featb, 128, Wc1, b1, h1b, h1b + 128, 256);
  // layer 2: K-half0 A = h1[:,0:128], K-half1 A = h1[:,128:256] (lda=256)
  k_gemm<false><<<(N_NODES + 63) / 64, 256, 0, stream>>>(
      h1b, h1b + 128, 256, Wc2, nullptr, Tlb, Trb, 128);
  k_final<<<N_NODES / 4, 256, 0, stream>>>(Tlb, Trb, rowStart, deg, col, b2, Wfc, bfc, out);
}

// Round 8
// 267.216 us; speedup vs baseline: 1.0439x; 1.0398x over previous
//
#include <hip/hip_runtime.h>
#include <math.h>

#define N_NODES  50000
#define N_EDGES  600000
#define NB_SCAN  ((N_NODES + 255) / 256)   // 196

typedef __attribute__((ext_vector_type(8))) short bf16x8;
typedef __attribute__((ext_vector_type(4))) float f32x4;
typedef unsigned int uint32;

__device__ __forceinline__ unsigned short f2bf(float x) {
  uint32 u = __builtin_bit_cast(uint32, x);
  u += 0x7FFFu + ((u >> 16) & 1u);   // round-to-nearest-even
  return (unsigned short)(u >> 16);
}
__device__ __forceinline__ float bf2f(uint32 lo16) {
  return __builtin_bit_cast(float, lo16 << 16);
}
__device__ __forceinline__ uint32 pack2(float a, float b) {
  return (uint32)f2bf(a) | ((uint32)f2bf(b) << 16);
}

// ---------------- fused prep: cvt feat, cvt W1, cvt W2, zero deg + col slack ----------------
#define PREP_FEAT_BLOCKS 12500   // 3.2M uint32 / 256
#define PREP_W_BLOCKS    256     // 65536 / 256
__global__ void k_prep(const float* __restrict__ feat, unsigned short* __restrict__ featb,
                       const float* __restrict__ W1l, const float* __restrict__ W1r,
                       unsigned short* __restrict__ Wc1,
                       const float* __restrict__ W2l, const float* __restrict__ W2r,
                       unsigned short* __restrict__ Wc2,
                       int* __restrict__ deg, int* __restrict__ colSlack) {
  const int bid = blockIdx.x, t = threadIdx.x;
  if (bid < PREP_FEAT_BLOCKS) {
    int i = bid * 256 + t;
    float2 v = ((const float2*)feat)[i];
    ((uint32*)featb)[i] = pack2(v.x, v.y);
  } else if (bid < PREP_FEAT_BLOCKS + PREP_W_BLOCKS) {
    int id = (bid - PREP_FEAT_BLOCKS) * 256 + t;
    int n = id >> 8, k = id & 255;
    float v = (k < 128) ? W1l[n * 128 + k] : W1r[n * 128 + (k - 128)];
    Wc1[id] = f2bf(v);
  } else if (bid < PREP_FEAT_BLOCKS + 2 * PREP_W_BLOCKS) {
    int id = (bid - PREP_FEAT_BLOCKS - PREP_W_BLOCKS) * 256 + t;
    int n = id >> 8, k = id & 255;
    float v = (n < 128) ? W2l[n * 256 + k] : W2r[(n - 128) * 256 + k];
    Wc2[id] = f2bf(v);
  } else {
    int i = (bid - PREP_FEAT_BLOCKS - 2 * PREP_W_BLOCKS) * 256 + t;
    if (i < N_NODES) deg[i] = 0;
    if (i < 64) colSlack[i] = 0;
  }
}
#define PREP_BLOCKS (PREP_FEAT_BLOCKS + 2 * PREP_W_BLOCKS + NB_SCAN)

// ---------------- CSR build ----------------
__global__ void k_count(const int* __restrict__ dst, int* __restrict__ deg) {
  int i = blockIdx.x * 256 + threadIdx.x;
  if (i < N_EDGES) atomicAdd(&deg[dst[i]], 1);
}

__global__ void k_scanA(const int* __restrict__ deg, int* __restrict__ partial,
                        int* __restrict__ blockSums) {
  __shared__ int s[256];
  int t = threadIdx.x;
  int i = blockIdx.x * 256 + t;
  int v = (i < N_NODES) ? deg[i] : 0;
  s[t] = v; __syncthreads();
  for (int off = 1; off < 256; off <<= 1) {
    int y = (t >= off) ? s[t - off] : 0;
    __syncthreads();
    s[t] += y;
    __syncthreads();
  }
  if (i < N_NODES) partial[i] = s[t] - v;
  if (t == 255) blockSums[blockIdx.x] = s[255];
}

__global__ void k_scanB(int* __restrict__ blockSums, int nb) {
  __shared__ int s[256];
  int t = threadIdx.x;
  int v = (t < nb) ? blockSums[t] : 0;
  s[t] = v; __syncthreads();
  for (int off = 1; off < 256; off <<= 1) {
    int y = (t >= off) ? s[t - off] : 0;
    __syncthreads();
    s[t] += y;
    __syncthreads();
  }
  if (t < nb) blockSums[t] = s[t] - v;
}

__global__ void k_scanC(int* __restrict__ rowStart, const int* __restrict__ blockSums,
                        int* __restrict__ cursor) {
  int i = blockIdx.x * 256 + threadIdx.x;
  if (i < N_NODES) {
    int r = rowStart[i] + blockSums[blockIdx.x];
    rowStart[i] = r;
    cursor[i] = r;
  }
}

__global__ void k_fill(const int* __restrict__ src, const int* __restrict__ dst,
                       int* __restrict__ cursor, int* __restrict__ col) {
  int i = blockIdx.x * 256 + threadIdx.x;
  if (i < N_EDGES) {
    int p = atomicAdd(&cursor[dst[i]], 1);
    col[p] = src[i];
  }
}

// ---------------- 8-deep gather-mean core ----------------
template<int STRIDE>
__device__ __forceinline__ void gather8(const uint32* __restrict__ base,
                                        const int* __restrict__ col,
                                        int rs, int dg, int lane,
                                        float& s0, float& s1) {
  int idx[8];
  #pragma unroll
  for (int q = 0; q < 8; ++q) idx[q] = col[rs + q];
  float a0[8] = {}, a1[8] = {};
  int j = 0;
  for (; j + 8 <= dg; j += 8) {
    uint32 v[8];
    #pragma unroll
    for (int q = 0; q < 8; ++q) v[q] = base[(size_t)idx[q] * STRIDE + lane];
    #pragma unroll
    for (int q = 0; q < 8; ++q) idx[q] = col[rs + j + 8 + q];
    #pragma unroll
    for (int q = 0; q < 8; ++q) {
      a0[q] += bf2f(v[q] & 0xffffu);
      a1[q] += bf2f(v[q] >> 16);
    }
  }
  #pragma unroll
  for (int q = 0; q < 7; ++q) {
    if (j + q < dg) {
      uint32 v = base[(size_t)idx[q] * STRIDE + lane];
      a0[q] += bf2f(v & 0xffffu);
      a1[q] += bf2f(v >> 16);
    }
  }
  s0 = ((a0[0] + a0[1]) + (a0[2] + a0[3])) + ((a0[4] + a0[5]) + (a0[6] + a0[7]));
  s1 = ((a1[0] + a1[1]) + (a1[2] + a1[3])) + ((a1[4] + a1[5]) + (a1[6] + a1[7]));
}

// ---------------- layer-1 aggregation: one wave per node over featb ----------------
__global__ void k_agg1(const unsigned short* __restrict__ x, const int* __restrict__ rowStart,
                       const int* __restrict__ deg, const int* __restrict__ col,
                       unsigned short* __restrict__ agg) {
  int lane = threadIdx.x & 63;
  int n = blockIdx.x * 4 + (threadIdx.x >> 6);
  int rs = rowStart[n], dg = deg[n];
  float s0, s1;
  gather8<64>((const uint32*)x, col, rs, dg, lane, s0, s1);
  float inv = 1.0f / fmaxf((float)dg, 1.0f);
  ((uint32*)agg)[(size_t)n * 64 + lane] = pack2(s0 * inv, s1 * inv);
}

// ---------------- layer-1 MFMA GEMM ----------------
// h1[M][256] = relu(normalize([A0|A1](K=256) @ W^T + b)), A0/A1 lda=128.
// block = 4 waves; wave = 16 rows x 256 cols (norm needs the full row in-wave).
// K staged in 4 slices of 64: W-slice = 256 cols x 64 k = 32 KB LDS, layout
// [qp 0..7][n 0..255] in 16B chunks (qp = 8-k chunk) => ds_read_b128 2-way = free.
// 3 blocks/CU (grid 782 ~ 3.05/CU); acc 64 AGPR + ~50 VGPR, no spill at 170 cap.
__global__ __launch_bounds__(256, 3) void k_gemm1(
    const unsigned short* __restrict__ A0, const unsigned short* __restrict__ A1,
    const unsigned short* __restrict__ W, const float* __restrict__ bias,
    unsigned short* __restrict__ Y) {
  __shared__ unsigned short Ws[2048 * 8];  // 32 KB
  const int t = threadIdx.x, lane = t & 63, w = t >> 6;
  const int mi = lane & 15, quad = lane >> 4;
  const int m0 = blockIdx.x * 64 + w * 16;
  const int rowA = min(m0 + mi, N_NODES - 1);

  f32x4 acc[16];
  #pragma unroll
  for (int nt = 0; nt < 16; ++nt) acc[nt] = (f32x4){0.f, 0.f, 0.f, 0.f};

  #pragma unroll
  for (int ks = 0; ks < 4; ++ks) {
    if (ks) __syncthreads();           // all waves done reading previous slice
    // stage W slice ks: 2048 16B chunks, 8 instrs/wave
    #pragma unroll
    for (int i = 0; i < 8; ++i) {
      int ch0 = (w * 8 + i) * 64;      // wave-uniform
      int qp = ch0 >> 8, n0 = ch0 & 255;
      const unsigned short* gp = W + (size_t)(n0 + lane) * 256 + ks * 64 + qp * 8;
      unsigned short* lp = Ws + (size_t)ch0 * 8;
      __builtin_amdgcn_global_load_lds(
          (const __attribute__((address_space(1))) void*)gp,
          (__attribute__((address_space(3))) void*)lp, 16, 0, 0);
    }
    // A fragments for this slice (k in [ks*64, ks*64+64))
    const unsigned short* Asrc = (ks < 2) ? A0 : A1;
    const int koff = (ks & 1) * 64;
    bf16x8 af0 = *(const bf16x8*)(Asrc + (size_t)rowA * 128 + koff + quad * 8);
    bf16x8 af1 = *(const bf16x8*)(Asrc + (size_t)rowA * 128 + koff + 32 + quad * 8);
    __syncthreads();                   // W slice + A frags ready
    #pragma unroll
    for (int nt = 0; nt < 16; ++nt) {
      bf16x8 b0 = *(const bf16x8*)(Ws + ((size_t)quad * 256 + nt * 16 + mi) * 8);
      acc[nt] = __builtin_amdgcn_mfma_f32_16x16x32_bf16(af0, b0, acc[nt], 0, 0, 0);
      bf16x8 b1 = *(const bf16x8*)(Ws + ((size_t)(4 + quad) * 256 + nt * 16 + mi) * 8);
      acc[nt] = __builtin_amdgcn_mfma_f32_16x16x32_bf16(af1, b1, acc[nt], 0, 0, 0);
    }
  }

  // epilogue: +bias, row L2-normalize, relu
  float ss[4] = {};
  #pragma unroll
  for (int nt = 0; nt < 16; ++nt) {
    float bv = bias[nt * 16 + mi];
    #pragma unroll
    for (int r = 0; r < 4; ++r) {
      float v = acc[nt][r] + bv;
      acc[nt][r] = v;
      ss[r] += v * v;
    }
  }
  #pragma unroll
  for (int r = 0; r < 4; ++r) {
    float s = ss[r];
    s += __shfl_xor(s, 1, 64);
    s += __shfl_xor(s, 2, 64);
    s += __shfl_xor(s, 4, 64);
    s += __shfl_xor(s, 8, 64);
    ss[r] = 1.0f / fmaxf(sqrtf(s), 1e-12f);
  }
  #pragma unroll
  for (int r = 0; r < 4; ++r) {
    int row = m0 + quad * 4 + r;
    if (row < N_NODES) {
      #pragma unroll
      for (int nt = 0; nt < 16; ++nt)
        Y[(size_t)row * 256 + nt * 16 + mi] = f2bf(fmaxf(acc[nt][r] * ss[r], 0.f));
    }
  }
}

// ---------------- layer-2 MFMA GEMM (no norm), col-split blocks ----------------
// T[M][256] = [A0|A1](K=256, lda=256) @ W^T ; block handles 128 rows x 128 cols
// (col-half chh: 0 -> Tl, 1 -> Tr). wave = 32 rows (2 rt) x 128 cols: each B
// ds_read feeds 2 MFMAs. K staged in 2 slices of 128: W-slice = 128 cols x 128 k
// = 32 KB, layout [qp 0..15][n 0..127] 16B chunks.
__global__ __launch_bounds__(256, 3) void k_gemm2(
    const unsigned short* __restrict__ A0, const unsigned short* __restrict__ A1,
    const unsigned short* __restrict__ W,
    unsigned short* __restrict__ Yl, unsigned short* __restrict__ Yr) {
  __shared__ unsigned short Ws[2048 * 8];  // 32 KB
  const int t = threadIdx.x, lane = t & 63, w = t >> 6;
  const int mi = lane & 15, quad = lane >> 4;
  const int rb = blockIdx.x >> 1, chh = blockIdx.x & 1;
  const int m0 = rb * 128 + w * 32;
  const int col0 = chh * 128;
  const int rowA0 = min(m0 + mi, N_NODES - 1);
  const int rowA1 = min(m0 + 16 + mi, N_NODES - 1);

  f32x4 acc[2][8];
  #pragma unroll
  for (int rt = 0; rt < 2; ++rt)
    #pragma unroll
    for (int nt = 0; nt < 8; ++nt) acc[rt][nt] = (f32x4){0.f, 0.f, 0.f, 0.f};

  #pragma unroll
  for (int ks = 0; ks < 2; ++ks) {
    if (ks) __syncthreads();
    // stage W slice: cols [col0, col0+128) x k [ks*128, +128)
    #pragma unroll
    for (int i = 0; i < 8; ++i) {
      int ch0 = (w * 8 + i) * 64;      // wave-uniform
      int qp = ch0 >> 7, n0 = ch0 & 127;
      const unsigned short* gp = W + (size_t)(col0 + n0 + lane) * 256 + ks * 128 + qp * 8;
      unsigned short* lp = Ws + (size_t)ch0 * 8;
      __builtin_amdgcn_global_load_lds(
          (const __attribute__((address_space(1))) void*)gp,
          (__attribute__((address_space(3))) void*)lp, 16, 0, 0);
    }
    const unsigned short* Asrc = ks ? A1 : A0;
    bf16x8 af[2][4];
    #pragma unroll
    for (int c = 0; c < 4; ++c) {
      af[0][c] = *(const bf16x8*)(Asrc + (size_t)rowA0 * 256 + c * 32 + quad * 8);
      af[1][c] = *(const bf16x8*)(Asrc + (size_t)rowA1 * 256 + c * 32 + quad * 8);
    }
    __syncthreads();
    #pragma unroll
    for (int c = 0; c < 4; ++c)
      #pragma unroll
      for (int nt = 0; nt < 8; ++nt) {
        bf16x8 b = *(const bf16x8*)(Ws + ((size_t)(c * 4 + quad) * 128 + nt * 16 + mi) * 8);
        acc[0][nt] = __builtin_amdgcn_mfma_f32_16x16x32_bf16(af[0][c], b, acc[0][nt], 0, 0, 0);
        acc[1][nt] = __builtin_amdgcn_mfma_f32_16x16x32_bf16(af[1][c], b, acc[1][nt], 0, 0, 0);
      }
  }

  unsigned short* Y = chh ? Yr : Yl;
  #pragma unroll
  for (int rt = 0; rt < 2; ++rt)
    #pragma unroll
    for (int r = 0; r < 4; ++r) {
      int row = m0 + rt * 16 + quad * 4 + r;
      if (row < N_NODES) {
        #pragma unroll
        for (int nt = 0; nt < 8; ++nt)
          Y[(size_t)row * 128 + nt * 16 + mi] = f2bf(acc[rt][nt][r]);
      }
    }
}

// ---------------- fused layer-2 tail ----------------
__global__ void k_final(const unsigned short* __restrict__ Tl, const unsigned short* __restrict__ Tr,
                        const int* __restrict__ rowStart, const int* __restrict__ deg,
                        const int* __restrict__ col,
                        const float* __restrict__ b2, const float* __restrict__ Wfc,
                        const float* __restrict__ bfc, float* __restrict__ out) {
  int lane = threadIdx.x & 63;
  int n = blockIdx.x * 4 + (threadIdx.x >> 6);
  int rs = rowStart[n], dg = deg[n];
  float s0, s1;
  gather8<64>((const uint32*)Tl, col, rs, dg, lane, s0, s1);
  float inv = 1.0f / fmaxf((float)dg, 1.0f);
  uint32 tv = ((const uint32*)Tr)[(size_t)n * 64 + lane];
  int d = lane * 2;
  float h0 = s0 * inv + bf2f(tv & 0xffffu) + b2[d];
  float h1 = s1 * inv + bf2f(tv >> 16) + b2[d + 1];
  float ss = h0 * h0 + h1 * h1;
  #pragma unroll
  for (int m = 1; m < 64; m <<= 1) ss += __shfl_xor(ss, m, 64);
  float iv = 1.0f / fmaxf(sqrtf(ss), 1e-12f);
  h0 *= iv; h1 *= iv;
  float p0 = h0 * Wfc[d] + h1 * Wfc[d + 1];
  float p1 = h0 * Wfc[128 + d] + h1 * Wfc[128 + d + 1];
  #pragma unroll
  for (int m = 1; m < 64; m <<= 1) {
    p0 += __shfl_xor(p0, m, 64);
    p1 += __shfl_xor(p1, m, 64);
  }
  if (lane == 0) {
    float l0 = p0 + bfc[0], l1 = p1 + bfc[1];
    float mx = fmaxf(l0, l1);
    float e0 = expf(l0 - mx), e1 = expf(l1 - mx);
    float s = 1.0f / (e0 + e1);
    out[(size_t)n * 2 + 0] = e0 * s;
    out[(size_t)n * 2 + 1] = e1 * s;
  }
}

extern "C" void kernel_launch(void* const* d_in, const int* in_sizes, int n_in,
                              void* d_out, int out_size, void* d_ws, size_t ws_size,
                              hipStream_t stream) {
  const float* feat = (const float*)d_in[0];
  const int* eidx = (const int*)d_in[1];
  const int* src = eidx;
  const int* dst = eidx + N_EDGES;
  const float* W1l = (const float*)d_in[2];
  const float* b1  = (const float*)d_in[3];
  const float* W1r = (const float*)d_in[4];
  const float* W2l = (const float*)d_in[5];
  const float* b2  = (const float*)d_in[6];
  const float* W2r = (const float*)d_in[7];
  const float* Wfc = (const float*)d_in[8];
  const float* bfc = (const float*)d_in[9];
  float* out = (float*)d_out;

  // workspace layout (all 16B aligned)
  int* deg       = (int*)d_ws;
  int* rowStart  = deg + 50176;
  int* cursor    = rowStart + 50176;
  int* blockSums = cursor + 50176;
  int* col       = blockSums + 256;                        // 600064 (64 slack, zeroed by k_prep)
  unsigned short* featb = (unsigned short*)(col + 600064); // 50000*128
  unsigned short* agg1b = featb + 6400000;                 // 50000*128
  unsigned short* h1b   = agg1b + 6400000;                 // 50000*256
  unsigned short* Tlb   = h1b + 12800000;                  // 50000*128
  unsigned short* Trb   = Tlb + 6400000;                   // 50000*128
  unsigned short* Wc1   = Trb + 6400000;                   // 256*256
  unsigned short* Wc2   = Wc1 + 65536;                     // 256*256

  k_prep<<<PREP_BLOCKS, 256, 0, stream>>>(feat, featb, W1l, W1r, Wc1,
                                          W2l, W2r, Wc2, deg, col + N_EDGES);
  k_count<<<(N_EDGES + 255) / 256, 256, 0, stream>>>(dst, deg);
  k_scanA<<<NB_SCAN, 256, 0, stream>>>(deg, rowStart, blockSums);
  k_scanB<<<1, 256, 0, stream>>>(blockSums, NB_SCAN);
  k_scanC<<<NB_SCAN, 256, 0, stream>>>(rowStart, blockSums, cursor);
  k_fill<<<(N_EDGES + 255) / 256, 256, 0, stream>>>(src, dst, cursor, col);

  k_agg1<<<N_NODES / 4, 256, 0, stream>>>(featb, rowStart, deg, col, agg1b);
  // layer 1: K 0..127 from agg1b, 128..255 from featb (both lda=128)
  k_gemm1<<<(N_NODES + 63) / 64, 256, 0, stream>>>(agg1b, featb, Wc1, b1, h1b);
  // layer 2: K 0..127 from h1[:,0:128], 128..255 from h1[:,128:256]; outputs Tl/Tr
  k_gemm2<<<2 * ((N_NODES + 127) / 128), 256, 0, stream>>>(h1b, h1b + 128, Wc2, Tlb, Trb);
  k_final<<<N_NODES / 4, 256, 0, stream>>>(Tlb, Trb, rowStart, deg, col, b2, Wfc, bfc, out);
}